// Round 2
// baseline (313.361 us; speedup 1.0000x reference)
//
#include <hip/hip_runtime.h>

#define LOG2E 1.44269504088896340736f

typedef _Float16 f16;
typedef __attribute__((ext_vector_type(2))) _Float16 f16x2;
typedef __attribute__((ext_vector_type(4))) _Float16 f16x4;
typedef __attribute__((ext_vector_type(8))) _Float16 f16x8;
typedef __attribute__((ext_vector_type(4))) float f32x4;
typedef __attribute__((ext_vector_type(16))) float f32x16;
typedef __attribute__((ext_vector_type(8))) unsigned short us8;

#define BB 32
#define SSX 2048
#define SSY 2048
#define DD 160
#define M_TOTAL (BB*SSX)   // 65536

#define PRS 168    // proj LDS row stride (f16)
#define VTRS 136   // proj V^T store buffer stride
#define KST 160    // flash K/Q LDS stride (XOR slot swizzle, no pad)

__device__ __forceinline__ f32x4 mfma16(f16x8 a, f16x8 b, f32x4 c) {
  return __builtin_amdgcn_mfma_f32_16x16x32_f16(a, b, c, 0, 0, 0);
}

__device__ __forceinline__ f32x16 mfma32(f16x8 a, f16x8 b, f32x16 c) {
  return __builtin_amdgcn_mfma_f32_32x32x16_f16(a, b, c, 0, 0, 0);
}

// RNE pack of two f32 -> u32 of 2 f16 (low = a)
__device__ __forceinline__ unsigned pk2(float a, float b) {
  union { f16x2 h; unsigned u; } x;
  x.h = (f16x2){(f16)a, (f16)b};
  return x.u;
}

// ---- Projection: one projection per block (kind 0=Q,1=K,2=V), 128-row tiles.
// XCD swizzle groups (Q,K,V) triples + consecutive tiles per XCD (y/x L2 reuse).
__global__ __launch_bounds__(256, 3) void proj_kernel(
    const float* __restrict__ x, const float* __restrict__ y,
    const float* __restrict__ Wq, const float* __restrict__ bq,
    const float* __restrict__ Wk, const float* __restrict__ bk,
    const float* __restrict__ Wv, const float* __restrict__ bv,
    f16* __restrict__ Qw, f16* __restrict__ Kw, f16* __restrict__ Vtw)
{
  __shared__ __align__(16) f16 buf[160*PRS];   // 53760 B -> 3 blocks/CU
  const int t = threadIdx.x;
  const int wave = t >> 6;
  const int lane = t & 63;
  const int quad = lane >> 4;
  const int l16  = lane & 15;
  // 1536 blocks = 8 XCDs x 192: each XCD gets contiguous logical range
  const int bid  = (blockIdx.x & 7) * 192 + (blockIdx.x >> 3);
  const int kind = bid % 3;          // 0=Q, 1=K, 2=V (K,V same tile adjacent -> L2 reuse of y)
  const int tile = bid / 3;
  const int row0 = tile * 128;
  const float* src  = (kind == 0) ? x  : y;
  const float* W    = (kind == 0) ? Wq : (kind == 1 ? Wk : Wv);
  const float* bias = (kind == 0) ? bq : (kind == 1 ? bk : bv);

  for (int i = 0; i < 20; ++i) {
    int idx = t + i*256;
    int r = idx / 40, c4 = idx % 40;
    float4 v = *(const float4*)&src[(size_t)(row0 + r)*DD + c4*4];
    f16x4 h = { (f16)v.x, (f16)v.y, (f16)v.z, (f16)v.w };
    *(f16x4*)&buf[r*PRS + c4*4] = h;
  }
  __syncthreads();
  f16x8 afr0[5], afr1[5];
  #pragma unroll
  for (int ks = 0; ks < 5; ++ks) {
    afr0[ks] = *(const f16x8*)&buf[(wave*32 + l16)*PRS + ks*32 + quad*8];
    afr1[ks] = *(const f16x8*)&buf[(wave*32 + 16 + l16)*PRS + ks*32 + quad*8];
  }
  __syncthreads();

  for (int i = 0; i < 25; ++i) {
    int idx = t + i*256;
    int r = idx / 40, c4 = idx % 40;
    float4 v = *(const float4*)&W[r*160 + c4*4];
    f16x4 h = { (f16)v.x, (f16)v.y, (f16)v.z, (f16)v.w };
    *(f16x4*)&buf[r*PRS + c4*4] = h;
  }
  __syncthreads();

  f32x4 acc0[10], acc1[10];
  #pragma unroll
  for (int nt = 0; nt < 10; ++nt) {
    float bs = bias[nt*16 + l16];
    acc0[nt] = (f32x4){bs,bs,bs,bs};
    acc1[nt] = (f32x4){bs,bs,bs,bs};
    #pragma unroll
    for (int ks = 0; ks < 5; ++ks) {
      f16x8 bfr = *(const f16x8*)&buf[(nt*16 + l16)*PRS + ks*32 + quad*8];
      acc0[nt] = mfma16(afr0[ks], bfr, acc0[nt]);
      acc1[nt] = mfma16(afr1[ks], bfr, acc1[nt]);
    }
  }
  __syncthreads();

  if (kind < 2) {
    f16* dst = (kind == 0) ? Qw : Kw;
    #pragma unroll
    for (int nt = 0; nt < 10; ++nt)
      #pragma unroll
      for (int r = 0; r < 4; ++r) {
        buf[(wave*32 + quad*4 + r)*PRS + nt*16 + l16]      = (f16)acc0[nt][r];
        buf[(wave*32 + 16 + quad*4 + r)*PRS + nt*16 + l16] = (f16)acc1[nt][r];
      }
    __syncthreads();
    for (int i = 0; i < 10; ++i) {
      int idx = t + i*256;
      int r = idx / 20, g = idx % 20;
      *(us8*)&dst[(size_t)(row0 + r)*DD + g*8] = *(const us8*)&buf[r*PRS + g*8];
    }
  } else {
    #pragma unroll
    for (int nt = 0; nt < 10; ++nt)
      #pragma unroll
      for (int r = 0; r < 4; ++r) {
        buf[(nt*16 + l16)*VTRS + wave*32 + quad*4 + r]      = (f16)acc0[nt][r];
        buf[(nt*16 + l16)*VTRS + wave*32 + 16 + quad*4 + r] = (f16)acc1[nt][r];
      }
    __syncthreads();
    const int b  = row0 / SSY;
    const int y0 = row0 % SSY;
    for (int i = 0; i < 10; ++i) {
      int idx = t + i*256;
      int d = idx / 16, yg = idx % 16;
      *(us8*)&Vtw[((size_t)b*DD + d)*SSY + y0 + yg*8] = *(const us8*)&buf[d*VTRS + yg*8];
    }
  }
}

// ---------------- Flash attention + residual: 128 q-rows/block, 32 q-rows/wave ----------------
// Double-buffered K/V LDS: one barrier per yc, store overlaps compute.
// K layout: stride 160 f16, 16B-slot index c stored at c ^ ((row>>1)&3)  (4-way spread, same as pad-168)
// V layout: stride 64 f16, slot g stored at g ^ (row&7)

#define LOAD_CHUNK(yb) { \
  const f16* ksrc = Kw + ((size_t)b*SSY + (yb))*DD; \
  const f16* vsrc = Vtw + (size_t)b*DD*SSY + (yb); \
  _Pragma("unroll") \
  for (int i = 0; i < 5; ++i) { \
    int idx = t + i*256; int r = idx/20, c = idx%20; \
    kreg[i] = *(const us8*)&ksrc[(size_t)r*DD + c*8]; \
  } \
  _Pragma("unroll") \
  for (int i = 0; i < 5; ++i) { \
    int idx = t + i*256; int d = idx>>3, g = idx&7; \
    vreg[i] = *(const us8*)&vsrc[(size_t)d*SSY + g*8]; \
  } \
}

#define STORE_CHUNK(cb) { \
  _Pragma("unroll") \
  for (int i = 0; i < 5; ++i) { \
    int idx = t + i*256; int r = idx/20, c = idx%20; \
    *(us8*)&K_lds[cb][r*KST + ((c ^ ((r>>1)&3))<<3)] = kreg[i]; \
  } \
  _Pragma("unroll") \
  for (int i = 0; i < 5; ++i) { \
    int idx = t + i*256; int d = idx>>3, g = idx&7; \
    *(us8*)&Vt_lds[cb][d*64 + ((g ^ (d & 7))<<3)] = vreg[i]; \
  } \
}

__global__ __launch_bounds__(256, 2) void flash_kernel(
    const f16* __restrict__ Qw, const f16* __restrict__ Kw, const f16* __restrict__ Vtw,
    const float* __restrict__ x, float* __restrict__ out)
{
  __shared__ __align__(16) f16 K_lds[2][64*KST];    // 2 x 20480 B (buf0 doubles as Q staging)
  __shared__ __align__(16) f16 Vt_lds[2][160*64];   // 2 x 20480 B -> total 81920 B = 2 blocks/CU exact
  const int t = threadIdx.x;
  const int wave = t >> 6;
  const int lane = t & 63;
  const int l31  = lane & 31;
  const int hi   = lane >> 5;
  // 512 blocks = 8 XCDs x 64: each XCD owns 4 complete batches (K/V L2 reuse)
  const int bid  = (blockIdx.x & 7) * 64 + (blockIdx.x >> 3);
  const int b    = bid >> 4;
  const int x0   = (bid & 15) * 128;
  const int rot  = (l31 >> 1) & 3;

  us8 kreg[5], vreg[5];
  LOAD_CHUNK(0);   // overlap chunk-0 HBM latency with Q staging

  // stage Q (128 rows in two 64-row passes through K_lds[0]), hoist B-frags (32 rows/wave)
  f16x8 qfr[10];
  #pragma unroll
  for (int h = 0; h < 2; ++h) {
    if (h) __syncthreads();
    const f16* qsrc = Qw + ((size_t)b*SSX + x0 + h*64)*DD;
    for (int i = 0; i < 5; ++i) {
      int idx = t + i*256;
      int r = idx / 20, c = idx % 20;
      *(us8*)&K_lds[0][r*KST + ((c ^ ((r>>1)&3))<<3)] = *(const us8*)&qsrc[(size_t)r*DD + c*8];
    }
    __syncthreads();
    if ((wave >> 1) == h) {
      const int base = (wave & 1)*32;
      #pragma unroll
      for (int s = 0; s < 10; ++s)
        qfr[s] = *(const f16x8*)&K_lds[0][(base + l31)*KST + (((s*2 + hi) ^ rot)<<3)];
    }
  }
  __syncthreads();   // all qfr reads done before K_lds[0] overwrite

  f32x16 acc[5];
  #pragma unroll
  for (int i = 0; i < 5; ++i)
    #pragma unroll
    for (int r = 0; r < 16; ++r) acc[i][r] = 0.f;
  float m = -1e30f, l = 0.f;

  STORE_CHUNK(0);
  LOAD_CHUNK(64);    // chunk 1
  __syncthreads();   // buf0 visible

  for (int yc = 0; yc < SSY/64; ++yc) {
    const int cur = yc & 1;
    const f16* Kc = K_lds[cur];
    const f16* Vc = Vt_lds[cur];

    // S^T = K Q^T : rows = k (C-layout), cols = q = l31
    f32x16 S0, S1;
    #pragma unroll
    for (int r = 0; r < 16; ++r) { S0[r] = 0.f; S1[r] = 0.f; }
    __builtin_amdgcn_s_setprio(1);
    #pragma unroll
    for (int s = 0; s < 10; ++s) {
      f16x8 k0 = *(const f16x8*)&Kc[l31*KST + (((s*2 + hi) ^ rot)<<3)];
      f16x8 k1 = *(const f16x8*)&Kc[(32 + l31)*KST + (((s*2 + hi) ^ rot)<<3)];
      S0 = mfma32(k0, qfr[s], S0);
      S1 = mfma32(k1, qfr[s], S1);
    }
    __builtin_amdgcn_s_setprio(0);

    // store chunk yc+1 into the other buffer (overlaps softmax below)
    if (yc < SSY/64 - 1) STORE_CHUNK(cur ^ 1);
    // prefetch chunk yc+2
    if (yc < SSY/64 - 2) LOAD_CHUNK((yc+2)*64);

    // row max for q = l31: 32 in-lane values + cross-half
    float pmax = fmaxf(S0[0], S0[1]);
    #pragma unroll
    for (int r = 2; r < 16; r += 2) pmax = fmaxf(pmax, fmaxf(S0[r], S0[r+1]));
    #pragma unroll
    for (int r = 0; r < 16; r += 2) pmax = fmaxf(pmax, fmaxf(S1[r], S1[r+1]));
    pmax = fmaxf(pmax, __shfl_xor(pmax, 32));

    // defer-max: only rescale when max grows by > 8
    if (__any(pmax > m + 8.f)) {
      float n  = fmaxf(m, pmax);
      float sc = exp2f((m - n)*LOG2E);
      m = n; l *= sc;
      #pragma unroll
      for (int r = 0; r < 16; ++r) {
        float scq = __shfl(sc, (r&3) + 8*(r>>2) + 4*hi);
        #pragma unroll
        for (int dt = 0; dt < 5; ++dt) acc[dt][r] *= scq;
      }
    }

    // P = exp(S - m) in place; l accumulates f32 row sum
    float lsum = 0.f;
    #pragma unroll
    for (int r = 0; r < 16; ++r) { S0[r] = exp2f((S0[r] - m)*LOG2E); lsum += S0[r]; }
    #pragma unroll
    for (int r = 0; r < 16; ++r) { S1[r] = exp2f((S1[r] - m)*LOG2E); lsum += S1[r]; }
    lsum += __shfl_xor(lsum, 32);
    l += lsum;

    // register exchange C-layout -> A-layout per 16-k chunk, then PV
    #pragma unroll
    for (int c = 0; c < 4; ++c) {
      const int bo = (c & 1)*8;
      unsigned L0, L1, H0, H1;
      if (c < 2) {
        L0 = pk2(S0[bo+0], S0[bo+1]); L1 = pk2(S0[bo+2], S0[bo+3]);
        H0 = pk2(S0[bo+4], S0[bo+5]); H1 = pk2(S0[bo+6], S0[bo+7]);
      } else {
        L0 = pk2(S1[bo+0], S1[bo+1]); L1 = pk2(S1[bo+2], S1[bo+3]);
        H0 = pk2(S1[bo+4], S1[bo+5]); H1 = pk2(S1[bo+6], S1[bo+7]);
      }
      unsigned sd0 = hi ? L0 : H0;              // send the half the partner needs
      unsigned sd1 = hi ? L1 : H1;
      unsigned rc0 = (unsigned)__shfl_xor((int)sd0, 32);
      unsigned rc1 = (unsigned)__shfl_xor((int)sd1, 32);
      union { unsigned u[4]; f16x8 h; } pw;
      pw.u[0] = hi ? rc0 : L0;
      pw.u[1] = hi ? rc1 : L1;
      pw.u[2] = hi ? H0 : rc0;
      pw.u[3] = hi ? H1 : rc1;
      __builtin_amdgcn_s_setprio(1);
      #pragma unroll
      for (int dt = 0; dt < 5; ++dt) {
        int row = dt*32 + l31;
        f16x8 vf = *(const f16x8*)&Vc[row*64 + (((c*2 + hi) ^ (row & 7)) << 3)];
        acc[dt] = mfma32(pw.h, vf, acc[dt]);
      }
      __builtin_amdgcn_s_setprio(0);
    }

    __syncthreads();   // buf[cur^1] complete (stores) and consumed next iter
  }

  // epilogue: out = acc/l + x ; acc reg r holds q = (r&3)+8*(r>>2)+4*hi, col d = dt*32+l31
  #pragma unroll
  for (int r = 0; r < 16; ++r) {
    int qr = (r&3) + 8*(r>>2) + 4*hi;
    float rl = 1.f / __shfl(l, qr);
    size_t rowoff = ((size_t)b*SSX + x0 + wave*32 + qr)*DD + l31;
    #pragma unroll
    for (int dt = 0; dt < 5; ++dt) {
      size_t o = rowoff + (size_t)dt*32;
      out[o] = acc[dt][r]*rl + x[o];
    }
  }
}

extern "C" void kernel_launch(void* const* d_in, const int* in_sizes, int n_in,
                              void* d_out, int out_size, void* d_ws, size_t ws_size,
                              hipStream_t stream) {
  const float* x  = (const float*)d_in[0];
  const float* y  = (const float*)d_in[1];
  const float* Wq = (const float*)d_in[2];
  const float* bq = (const float*)d_in[3];
  const float* Wk = (const float*)d_in[4];
  const float* bk = (const float*)d_in[5];
  const float* Wv = (const float*)d_in[6];
  const float* bv = (const float*)d_in[7];

  f16* Qw  = (f16*)d_ws;
  f16* Kw  = Qw + (size_t)M_TOTAL*DD;
  f16* Vtw = Kw + (size_t)M_TOTAL*DD;   // 63 MB of workspace total

  proj_kernel<<<1536, 256, 0, stream>>>(x, y, Wq, bq, Wk, bk, Wv, bv, Qw, Kw, Vtw);
  flash_kernel<<<512, 256, 0, stream>>>(Qw, Kw, Vtw, x, (float*)d_out);
}

// Round 3
// 282.027 us; speedup vs baseline: 1.1111x; 1.1111x over previous
//
#include <hip/hip_runtime.h>

#define LOG2E 1.44269504088896340736f

typedef _Float16 f16;
typedef __attribute__((ext_vector_type(2))) _Float16 f16x2;
typedef __attribute__((ext_vector_type(4))) _Float16 f16x4;
typedef __attribute__((ext_vector_type(8))) _Float16 f16x8;
typedef __attribute__((ext_vector_type(4))) float f32x4;
typedef __attribute__((ext_vector_type(16))) float f32x16;
typedef __attribute__((ext_vector_type(8))) unsigned short us8;

#define BB 32
#define SSX 2048
#define SSY 2048
#define DD 160
#define M_TOTAL (BB*SSX)   // 65536

#define PRS 168    // proj LDS row stride (f16)
#define VTRS 136   // proj V^T store buffer stride
#define RS 168     // flash K/Q LDS stride (pad-8: const-offset ds_reads, 4-way max)

__device__ __forceinline__ f32x4 mfma16(f16x8 a, f16x8 b, f32x4 c) {
  return __builtin_amdgcn_mfma_f32_16x16x32_f16(a, b, c, 0, 0, 0);
}

__device__ __forceinline__ f32x16 mfma32(f16x8 a, f16x8 b, f32x16 c) {
  return __builtin_amdgcn_mfma_f32_32x32x16_f16(a, b, c, 0, 0, 0);
}

// RNE pack of two f32 -> u32 of 2 f16 (low = a)
__device__ __forceinline__ unsigned pk2(float a, float b) {
  union { f16x2 h; unsigned u; } x;
  x.h = (f16x2){(f16)a, (f16)b};
  return x.u;
}

// ---- Projection: one projection per block (kind 0=Q,1=K,2=V), 128-row tiles.
// XCD swizzle groups (Q,K,V) triples + consecutive tiles per XCD (y/x L2 reuse).
__global__ __launch_bounds__(256, 3) void proj_kernel(
    const float* __restrict__ x, const float* __restrict__ y,
    const float* __restrict__ Wq, const float* __restrict__ bq,
    const float* __restrict__ Wk, const float* __restrict__ bk,
    const float* __restrict__ Wv, const float* __restrict__ bv,
    f16* __restrict__ Qw, f16* __restrict__ Kw, f16* __restrict__ Vtw)
{
  __shared__ __align__(16) f16 buf[160*PRS];   // 53760 B -> 3 blocks/CU
  const int t = threadIdx.x;
  const int wave = t >> 6;
  const int lane = t & 63;
  const int quad = lane >> 4;
  const int l16  = lane & 15;
  // 1536 blocks = 8 XCDs x 192: each XCD gets contiguous logical range
  const int bid  = (blockIdx.x & 7) * 192 + (blockIdx.x >> 3);
  const int kind = bid % 3;          // 0=Q, 1=K, 2=V (K,V same tile adjacent -> L2 reuse of y)
  const int tile = bid / 3;
  const int row0 = tile * 128;
  const float* src  = (kind == 0) ? x  : y;
  const float* W    = (kind == 0) ? Wq : (kind == 1 ? Wk : Wv);
  const float* bias = (kind == 0) ? bq : (kind == 1 ? bk : bv);

  for (int i = 0; i < 20; ++i) {
    int idx = t + i*256;
    int r = idx / 40, c4 = idx % 40;
    float4 v = *(const float4*)&src[(size_t)(row0 + r)*DD + c4*4];
    f16x4 h = { (f16)v.x, (f16)v.y, (f16)v.z, (f16)v.w };
    *(f16x4*)&buf[r*PRS + c4*4] = h;
  }
  __syncthreads();
  f16x8 afr0[5], afr1[5];
  #pragma unroll
  for (int ks = 0; ks < 5; ++ks) {
    afr0[ks] = *(const f16x8*)&buf[(wave*32 + l16)*PRS + ks*32 + quad*8];
    afr1[ks] = *(const f16x8*)&buf[(wave*32 + 16 + l16)*PRS + ks*32 + quad*8];
  }
  __syncthreads();

  for (int i = 0; i < 25; ++i) {
    int idx = t + i*256;
    int r = idx / 40, c4 = idx % 40;
    float4 v = *(const float4*)&W[r*160 + c4*4];
    f16x4 h = { (f16)v.x, (f16)v.y, (f16)v.z, (f16)v.w };
    *(f16x4*)&buf[r*PRS + c4*4] = h;
  }
  __syncthreads();

  f32x4 acc0[10], acc1[10];
  #pragma unroll
  for (int nt = 0; nt < 10; ++nt) {
    float bs = bias[nt*16 + l16];
    acc0[nt] = (f32x4){bs,bs,bs,bs};
    acc1[nt] = (f32x4){bs,bs,bs,bs};
    #pragma unroll
    for (int ks = 0; ks < 5; ++ks) {
      f16x8 bfr = *(const f16x8*)&buf[(nt*16 + l16)*PRS + ks*32 + quad*8];
      acc0[nt] = mfma16(afr0[ks], bfr, acc0[nt]);
      acc1[nt] = mfma16(afr1[ks], bfr, acc1[nt]);
    }
  }
  __syncthreads();

  if (kind < 2) {
    f16* dst = (kind == 0) ? Qw : Kw;
    #pragma unroll
    for (int nt = 0; nt < 10; ++nt)
      #pragma unroll
      for (int r = 0; r < 4; ++r) {
        buf[(wave*32 + quad*4 + r)*PRS + nt*16 + l16]      = (f16)acc0[nt][r];
        buf[(wave*32 + 16 + quad*4 + r)*PRS + nt*16 + l16] = (f16)acc1[nt][r];
      }
    __syncthreads();
    for (int i = 0; i < 10; ++i) {
      int idx = t + i*256;
      int r = idx / 20, g = idx % 20;
      *(us8*)&dst[(size_t)(row0 + r)*DD + g*8] = *(const us8*)&buf[r*PRS + g*8];
    }
  } else {
    #pragma unroll
    for (int nt = 0; nt < 10; ++nt)
      #pragma unroll
      for (int r = 0; r < 4; ++r) {
        buf[(nt*16 + l16)*VTRS + wave*32 + quad*4 + r]      = (f16)acc0[nt][r];
        buf[(nt*16 + l16)*VTRS + wave*32 + 16 + quad*4 + r] = (f16)acc1[nt][r];
      }
    __syncthreads();
    const int b  = row0 / SSY;
    const int y0 = row0 % SSY;
    for (int i = 0; i < 10; ++i) {
      int idx = t + i*256;
      int d = idx / 16, yg = idx % 16;
      *(us8*)&Vtw[((size_t)b*DD + d)*SSY + y0 + yg*8] = *(const us8*)&buf[d*VTRS + yg*8];
    }
  }
}

// ---------------- Flash attention + residual: 128 q-rows/block, 32 q-rows/wave ----------------
// Round-1 structure (pad-168 K layout, const-offset ds_reads, 2 barriers/yc)
// + XCD-aware bid swizzle (the round-2 keeper: FETCH 199k->62k KB).

#define LOAD_CHUNK(yb) { \
  const f16* ksrc = Kw + ((size_t)b*SSY + (yb))*DD; \
  const f16* vsrc = Vtw + (size_t)b*DD*SSY + (yb); \
  _Pragma("unroll") \
  for (int i = 0; i < 5; ++i) { \
    int idx = t + i*256; int r = idx/20, c = idx%20; \
    kreg[i] = *(const us8*)&ksrc[(size_t)r*DD + c*8]; \
  } \
  _Pragma("unroll") \
  for (int i = 0; i < 5; ++i) { \
    int idx = t + i*256; int d = idx>>3, g = idx&7; \
    vreg[i] = *(const us8*)&vsrc[(size_t)d*SSY + g*8]; \
  } \
}

#define STORE_CHUNK() { \
  _Pragma("unroll") \
  for (int i = 0; i < 5; ++i) { \
    int idx = t + i*256; int r = idx/20, c = idx%20; \
    *(us8*)&K_lds[r*RS + c*8] = kreg[i]; \
  } \
  _Pragma("unroll") \
  for (int i = 0; i < 5; ++i) { \
    int idx = t + i*256; int d = idx>>3, g = idx&7; \
    *(us8*)&Vt_lds[d*64 + ((g ^ (d & 7)) << 3)] = vreg[i]; \
  } \
}

__global__ __launch_bounds__(256, 2) void flash_kernel(
    const f16* __restrict__ Qw, const f16* __restrict__ Kw, const f16* __restrict__ Vtw,
    const float* __restrict__ x, float* __restrict__ out)
{
  __shared__ __align__(16) f16 K_lds[64*RS];      // 21504 B (also Q staging)
  __shared__ __align__(16) f16 Vt_lds[160*64];    // 20480 B -> total 41984 B
  const int t = threadIdx.x;
  const int wave = t >> 6;
  const int lane = t & 63;
  const int l31  = lane & 31;
  const int hi   = lane >> 5;
  // 512 blocks = 8 XCDs x 64: each XCD owns 4 complete batches (K/V L2 reuse)
  const int bid  = (blockIdx.x & 7) * 64 + (blockIdx.x >> 3);
  const int b    = bid >> 4;
  const int x0   = (bid & 15) * 128;

  us8 kreg[5], vreg[5];
  LOAD_CHUNK(0);   // overlap chunk-0 HBM latency with Q staging

  // stage Q (128 rows in two 64-row passes through K_lds), hoist B-frags (32 rows/wave)
  f16x8 qfr[10];
  #pragma unroll
  for (int h = 0; h < 2; ++h) {
    if (h) __syncthreads();
    const f16* qsrc = Qw + ((size_t)b*SSX + x0 + h*64)*DD;
    for (int i = 0; i < 5; ++i) {
      int idx = t + i*256;
      int r = idx / 20, c = idx % 20;
      *(us8*)&K_lds[r*RS + c*8] = *(const us8*)&qsrc[(size_t)r*DD + c*8];
    }
    __syncthreads();
    if ((wave >> 1) == h) {
      const int base = (wave & 1)*32;
      #pragma unroll
      for (int s = 0; s < 10; ++s)
        qfr[s] = *(const f16x8*)&K_lds[(base + l31)*RS + s*16 + hi*8];
    }
  }

  f32x16 acc[5];
  #pragma unroll
  for (int i = 0; i < 5; ++i)
    #pragma unroll
    for (int r = 0; r < 16; ++r) acc[i][r] = 0.f;
  float m = -1e30f, l = 0.f;

  for (int yc = 0; yc < SSY/64; ++yc) {
    __syncthreads();          // A: prev compute done reading LDS (and qfr reads at yc=0)
    STORE_CHUNK();
    __syncthreads();          // B: LDS visible
    if (yc < SSY/64 - 1) LOAD_CHUNK((yc+1)*64);   // overlaps compute below

    // S^T = K Q^T : rows = k (C-layout), cols = q = l31
    f32x16 S0, S1;
    #pragma unroll
    for (int r = 0; r < 16; ++r) { S0[r] = 0.f; S1[r] = 0.f; }
    __builtin_amdgcn_s_setprio(1);
    #pragma unroll
    for (int s = 0; s < 10; ++s) {
      f16x8 k0 = *(const f16x8*)&K_lds[l31*RS + s*16 + hi*8];
      f16x8 k1 = *(const f16x8*)&K_lds[(32 + l31)*RS + s*16 + hi*8];
      S0 = mfma32(k0, qfr[s], S0);
      S1 = mfma32(k1, qfr[s], S1);
    }
    __builtin_amdgcn_s_setprio(0);

    // row max for q = l31: 32 in-lane values + cross-half
    float pmax = fmaxf(S0[0], S0[1]);
    #pragma unroll
    for (int r = 2; r < 16; r += 2) pmax = fmaxf(pmax, fmaxf(S0[r], S0[r+1]));
    #pragma unroll
    for (int r = 0; r < 16; r += 2) pmax = fmaxf(pmax, fmaxf(S1[r], S1[r+1]));
    pmax = fmaxf(pmax, __shfl_xor(pmax, 32));

    // defer-max: only rescale when max grows by > 8
    if (__any(pmax > m + 8.f)) {
      float n  = fmaxf(m, pmax);
      float sc = exp2f((m - n)*LOG2E);
      m = n; l *= sc;
      #pragma unroll
      for (int r = 0; r < 16; ++r) {
        float scq = __shfl(sc, (r&3) + 8*(r>>2) + 4*hi);
        #pragma unroll
        for (int dt = 0; dt < 5; ++dt) acc[dt][r] *= scq;
      }
    }

    // P = exp(S - m) in place; l accumulates f32 row sum
    float lsum = 0.f;
    #pragma unroll
    for (int r = 0; r < 16; ++r) { S0[r] = exp2f((S0[r] - m)*LOG2E); lsum += S0[r]; }
    #pragma unroll
    for (int r = 0; r < 16; ++r) { S1[r] = exp2f((S1[r] - m)*LOG2E); lsum += S1[r]; }
    lsum += __shfl_xor(lsum, 32);
    l += lsum;

    // register exchange C-layout -> A-layout per 16-k chunk, then PV
    #pragma unroll
    for (int c = 0; c < 4; ++c) {
      const int bo = (c & 1)*8;
      unsigned L0, L1, H0, H1;
      if (c < 2) {
        L0 = pk2(S0[bo+0], S0[bo+1]); L1 = pk2(S0[bo+2], S0[bo+3]);
        H0 = pk2(S0[bo+4], S0[bo+5]); H1 = pk2(S0[bo+6], S0[bo+7]);
      } else {
        L0 = pk2(S1[bo+0], S1[bo+1]); L1 = pk2(S1[bo+2], S1[bo+3]);
        H0 = pk2(S1[bo+4], S1[bo+5]); H1 = pk2(S1[bo+6], S1[bo+7]);
      }
      unsigned sd0 = hi ? L0 : H0;              // send the half the partner needs
      unsigned sd1 = hi ? L1 : H1;
      unsigned rc0 = (unsigned)__shfl_xor((int)sd0, 32);
      unsigned rc1 = (unsigned)__shfl_xor((int)sd1, 32);
      union { unsigned u[4]; f16x8 h; } pw;
      pw.u[0] = hi ? rc0 : L0;
      pw.u[1] = hi ? rc1 : L1;
      pw.u[2] = hi ? H0 : rc0;
      pw.u[3] = hi ? H1 : rc1;
      __builtin_amdgcn_s_setprio(1);
      #pragma unroll
      for (int dt = 0; dt < 5; ++dt) {
        int row = dt*32 + l31;
        f16x8 vf = *(const f16x8*)&Vt_lds[row*64 + (((c*2 + hi) ^ (row & 7)) << 3)];
        acc[dt] = mfma32(pw.h, vf, acc[dt]);
      }
      __builtin_amdgcn_s_setprio(0);
    }
  }

  // epilogue: out = acc/l + x ; acc reg r holds q = (r&3)+8*(r>>2)+4*hi, col d = dt*32+l31
  #pragma unroll
  for (int r = 0; r < 16; ++r) {
    int qr = (r&3) + 8*(r>>2) + 4*hi;
    float rl = 1.f / __shfl(l, qr);
    size_t rowoff = ((size_t)b*SSX + x0 + wave*32 + qr)*DD + l31;
    #pragma unroll
    for (int dt = 0; dt < 5; ++dt) {
      size_t o = rowoff + (size_t)dt*32;
      out[o] = acc[dt][r]*rl + x[o];
    }
  }
}

extern "C" void kernel_launch(void* const* d_in, const int* in_sizes, int n_in,
                              void* d_out, int out_size, void* d_ws, size_t ws_size,
                              hipStream_t stream) {
  const float* x  = (const float*)d_in[0];
  const float* y  = (const float*)d_in[1];
  const float* Wq = (const float*)d_in[2];
  const float* bq = (const float*)d_in[3];
  const float* Wk = (const float*)d_in[4];
  const float* bk = (const float*)d_in[5];
  const float* Wv = (const float*)d_in[6];
  const float* bv = (const float*)d_in[7];

  f16* Qw  = (f16*)d_ws;
  f16* Kw  = Qw + (size_t)M_TOTAL*DD;
  f16* Vtw = Kw + (size_t)M_TOTAL*DD;   // 63 MB of workspace total

  proj_kernel<<<1536, 256, 0, stream>>>(x, y, Wq, bq, Wk, bk, Wv, bv, Qw, Kw, Vtw);
  flash_kernel<<<512, 256, 0, stream>>>(Qw, Kw, Vtw, x, (float*)d_out);
}